// Round 2
// baseline (402.299 us; speedup 1.0000x reference)
//
#include <hip/hip_runtime.h>

#define NPTS 1024
#define NC 256
#define NH 360
#define NW 360
#define NHW (NH * NW)
#define NCHW (NC * NHW)
#define PPB 8  // points per block in MLP kernel

// ---------------------------------------------------------------------------
// Kernel 0: pure gather with maximal parallelism.
// One block per point (2048 blocks), one thread per channel.
// X[point][c] = feature[b, c, h, w]
// ---------------------------------------------------------------------------
__global__ __launch_bounds__(256) void gather_kernel(
    const float* __restrict__ feature,
    const int* __restrict__ idx1,
    const int* __restrict__ idx2,
    float* __restrict__ X)
{
    const int point = blockIdx.x;                 // 0..2047
    const int col = point & (NPTS - 1);
    const int* idx = (point < NPTS) ? idx1 : idx2;
    const int bb = idx[col];
    const int hh = idx[NPTS + col];
    const int ww = idx[2 * NPTS + col];
    const size_t base = (size_t)bb * NCHW + (size_t)hh * NW + ww;
    const int c = threadIdx.x;
    X[(size_t)point * NC + c] = feature[base + (size_t)c * NHW];
}

// ---------------------------------------------------------------------------
// Kernel 1: 3-layer MLP for 2048 points, 8 points/block, 512 threads (8 waves).
// Writes pq[2048][32]: rows 0..1023 = f1 @ w3, rows 1024..2047 = b3 - f2 @ w3.
// ---------------------------------------------------------------------------
__global__ __launch_bounds__(512) void mlp_kernel(
    const float* __restrict__ X,
    const float* __restrict__ w1, const float* __restrict__ b1,
    const float* __restrict__ w2, const float* __restrict__ b2,
    const float* __restrict__ w3, const float* __restrict__ b3,
    float* __restrict__ pq)
{
    __shared__ float Xs[PPB * 256];   // gathered inputs (8 KB)
    __shared__ float H1s[PPB * 256];  // layer-1 activations (8 KB)
    __shared__ float F2s[PPB * 128];  // layer-2 activations (4 KB)

    const int tid = threadIdx.x;      // 0..511
    const int base = blockIdx.x * PPB;

    // ---- load inputs: 8 contiguous rows of X (8 KB), fully coalesced ----
    {
        const float* src = X + (size_t)base * 256;
        #pragma unroll
        for (int i = 0; i < PPB * 256; i += 512)
            Xs[i + tid] = src[i + tid];
    }
    __syncthreads();

    // ---- layer 1: H1[p][j] = relu(sum_c X[p][c]*w1[c][j] + b1[j]) ----
    // j = tid & 255, each thread covers 4 of the 8 points.
    {
        const int j = tid & 255;
        const int half = tid >> 8;    // 0 or 1
        float acc[4] = {0.f, 0.f, 0.f, 0.f};
        #pragma unroll 4
        for (int c = 0; c < 256; ++c) {
            float wv = w1[c * 256 + j];            // coalesced, L2-resident
            #pragma unroll
            for (int q = 0; q < 4; ++q)
                acc[q] = fmaf(Xs[(half * 4 + q) * 256 + c], wv, acc[q]);
        }
        float bv = b1[j];
        #pragma unroll
        for (int q = 0; q < 4; ++q)
            H1s[(half * 4 + q) * 256 + j] = fmaxf(acc[q] + bv, 0.f);
    }
    __syncthreads();

    // ---- layer 2: F2[p][j] = relu(sum_c H1[p][c]*w2[c][j] + b2[j]) ----
    // j = tid & 127, each thread covers 2 of the 8 points.
    {
        const int j = tid & 127;
        const int quad = tid >> 7;    // 0..3
        float acc[2] = {0.f, 0.f};
        #pragma unroll 4
        for (int c = 0; c < 256; ++c) {
            float wv = w2[c * 128 + j];
            #pragma unroll
            for (int q = 0; q < 2; ++q)
                acc[q] = fmaf(H1s[(quad * 2 + q) * 256 + c], wv, acc[q]);
        }
        float bv = b2[j];
        #pragma unroll
        for (int q = 0; q < 2; ++q)
            F2s[(quad * 2 + q) * 128 + j] = fmaxf(acc[q] + bv, 0.f);
    }
    __syncthreads();

    // ---- layer 3 (no relu): pq[g][j] = sum_c F2[g][c]*w3[c][j] ----
    // Only 256 outputs per block: threads 0..255 do it, 128 FMAs each.
    if (tid < 256) {
        const int j = tid & 31;
        const int g = tid >> 5;       // 0..7
        float acc = 0.f;
        #pragma unroll 4
        for (int c = 0; c < 128; ++c)
            acc = fmaf(F2s[g * 128 + c], w3[c * 32 + j], acc);
        int point = base + g;
        float val = (point < NPTS) ? acc : (b3[j] - acc);
        pq[(size_t)point * 32 + j] = val;   // coalesced
    }
}

// ---------------------------------------------------------------------------
// Kernel 2: out[m][n] = b4 + sum_k w4[k] * relu(p1[m][k] + q2[n][k])
// Grid: (4 n-tiles, 128 m-tiles) = 512 blocks, 256 threads (one n, 8 m's).
// ---------------------------------------------------------------------------
__global__ __launch_bounds__(256) void pair_kernel(
    const float* __restrict__ pq,
    const float* __restrict__ w4,
    const float* __restrict__ b4,
    float* __restrict__ out)
{
    __shared__ float P1s[8 * 32];
    __shared__ float w4s[32];

    const int tid = threadIdx.x;
    const int n = blockIdx.x * 256 + tid;
    const int m0 = blockIdx.y * 8;

    // q2 row for this thread's n: 32 VGPRs
    float q[32];
    const float* q2 = pq + (size_t)(NPTS + n) * 32;
    #pragma unroll
    for (int k = 0; k < 32; ++k) q[k] = q2[k];

    // p1 tile (8 rows x 32) is contiguous
    if (tid < 8 * 32) P1s[tid] = pq[(size_t)m0 * 32 + tid];
    if (tid < 32) w4s[tid] = w4[tid];
    __syncthreads();

    const float b4v = b4[0];
    #pragma unroll
    for (int mm = 0; mm < 8; ++mm) {
        float acc = b4v;
        #pragma unroll
        for (int k = 0; k < 32; ++k) {
            float t = P1s[mm * 32 + k] + q[k];       // LDS broadcast + VGPR
            acc = fmaf(w4s[k], fmaxf(t, 0.f), acc);
        }
        out[(size_t)(m0 + mm) * 1024 + n] = acc;     // coalesced over n
    }
}

extern "C" void kernel_launch(void* const* d_in, const int* in_sizes, int n_in,
                              void* d_out, int out_size, void* d_ws, size_t ws_size,
                              hipStream_t stream) {
    const float* feature = (const float*)d_in[0];
    const int*   idx1    = (const int*)d_in[1];
    const int*   idx2    = (const int*)d_in[2];
    const float* w1      = (const float*)d_in[3];
    const float* b1      = (const float*)d_in[4];
    const float* w2      = (const float*)d_in[5];
    const float* b2      = (const float*)d_in[6];
    const float* w3      = (const float*)d_in[7];
    const float* b3      = (const float*)d_in[8];
    const float* w4      = (const float*)d_in[9];
    const float* b4      = (const float*)d_in[10];
    float* out = (float*)d_out;

    float* X  = (float*)d_ws;                       // 2048*256*4 = 2 MB
    float* pq = (float*)d_ws + 2048 * 256;          // 2048*32*4 = 256 KB

    gather_kernel<<<2048, 256, 0, stream>>>(feature, idx1, idx2, X);

    mlp_kernel<<<2048 / PPB, 512, 0, stream>>>(
        X, w1, b1, w2, b2, w3, b3, pq);

    pair_kernel<<<dim3(4, 128), 256, 0, stream>>>(pq, w4, b4, out);
}

// Round 3
// 380.132 us; speedup vs baseline: 1.0583x; 1.0583x over previous
//
#include <hip/hip_runtime.h>

#define NPTS 1024
#define NC 256
#define NH 360
#define NW 360
#define NHW (NH * NW)
#define NCHW (NC * NHW)
#define PPB 8       // points per MLP block
#define PAD 12      // LDS row stride for [c][p] activation tiles (breaks bank conflicts)

// ---------------------------------------------------------------------------
// Kernel 0: pure gather with maximal parallelism.
// One block per point (2048 blocks), one thread per channel.
// ---------------------------------------------------------------------------
__global__ __launch_bounds__(256) void gather_kernel(
    const float* __restrict__ feature,
    const int* __restrict__ idx1,
    const int* __restrict__ idx2,
    float* __restrict__ X)
{
    const int point = blockIdx.x;                 // 0..2047
    const int col = point & (NPTS - 1);
    const int* idx = (point < NPTS) ? idx1 : idx2;
    const int bb = idx[col];
    const int hh = idx[NPTS + col];
    const int ww = idx[2 * NPTS + col];
    const size_t base = (size_t)bb * NCHW + (size_t)hh * NW + ww;
    const int c = threadIdx.x;
    X[(size_t)point * NC + c] = feature[base + (size_t)c * NHW];
}

// ---------------------------------------------------------------------------
// Kernel 1: register-tiled 3-layer MLP. 8 points/block, 256 threads, 256 blocks.
// Activations in LDS transposed [c][p] (stride PAD) -> broadcast ds_read_b64
// feeds 8 FMAs; weights streamed as coalesced float4/float2 from L2.
// Writes pq[2048][32]: rows 0..1023 = f1 @ w3, rows 1024..2047 = b3 - f2 @ w3.
// ---------------------------------------------------------------------------
__global__ __launch_bounds__(256) void mlp_kernel(
    const float* __restrict__ X,
    const float* __restrict__ w1, const float* __restrict__ b1,
    const float* __restrict__ w2, const float* __restrict__ b2,
    const float* __restrict__ w3, const float* __restrict__ b3,
    float* __restrict__ pq)
{
    __shared__ float Xs[256 * PAD];   // [c][p], 12 KB
    __shared__ float H1s[256 * PAD];  // [j][p], 12 KB
    __shared__ float F2s[128 * PAD];  // [j][p], 6 KB

    const int tid = threadIdx.x;      // 0..255
    const int base = blockIdx.x * PPB;

    // ---- stage inputs transposed: Xs[c][p] = X[base+p][c] ----
    {
        const float* src = X + (size_t)base * 256;
        #pragma unroll
        for (int p = 0; p < PPB; ++p)
            Xs[tid * PAD + p] = src[p * 256 + tid];   // read coalesced over c=tid
    }
    __syncthreads();

    const int jt = tid & 63;          // lane group over output channels
    const int pt = tid >> 6;          // 0..3
    const int p0 = pt * 2;

    // ---- layer 1: 256 -> 256, each thread: 2 points x 4 outputs ----
    {
        const float4* w1v = (const float4*)w1;   // w1v[c*64 + jt] = w1[c*256 + 4*jt ..]
        float acc0[4] = {0.f, 0.f, 0.f, 0.f};
        float acc1[4] = {0.f, 0.f, 0.f, 0.f};
        #pragma unroll 8
        for (int c = 0; c < 256; ++c) {
            float4 wv = w1v[c * 64 + jt];
            float a0 = Xs[c * PAD + p0];
            float a1 = Xs[c * PAD + p0 + 1];
            acc0[0] = fmaf(a0, wv.x, acc0[0]);
            acc0[1] = fmaf(a0, wv.y, acc0[1]);
            acc0[2] = fmaf(a0, wv.z, acc0[2]);
            acc0[3] = fmaf(a0, wv.w, acc0[3]);
            acc1[0] = fmaf(a1, wv.x, acc1[0]);
            acc1[1] = fmaf(a1, wv.y, acc1[1]);
            acc1[2] = fmaf(a1, wv.z, acc1[2]);
            acc1[3] = fmaf(a1, wv.w, acc1[3]);
        }
        const int j0 = jt * 4;
        #pragma unroll
        for (int q = 0; q < 4; ++q) {
            float bv = b1[j0 + q];
            H1s[(j0 + q) * PAD + p0]     = fmaxf(acc0[q] + bv, 0.f);
            H1s[(j0 + q) * PAD + p0 + 1] = fmaxf(acc1[q] + bv, 0.f);
        }
    }
    __syncthreads();

    // ---- layer 2: 256 -> 128, each thread: 2 points x 2 outputs ----
    {
        const float2* w2v = (const float2*)w2;   // w2v[c*64 + jt] = w2[c*128 + 2*jt ..]
        float acc0[2] = {0.f, 0.f};
        float acc1[2] = {0.f, 0.f};
        #pragma unroll 8
        for (int c = 0; c < 256; ++c) {
            float2 wv = w2v[c * 64 + jt];
            float a0 = H1s[c * PAD + p0];
            float a1 = H1s[c * PAD + p0 + 1];
            acc0[0] = fmaf(a0, wv.x, acc0[0]);
            acc0[1] = fmaf(a0, wv.y, acc0[1]);
            acc1[0] = fmaf(a1, wv.x, acc1[0]);
            acc1[1] = fmaf(a1, wv.y, acc1[1]);
        }
        const int j0 = jt * 2;
        #pragma unroll
        for (int q = 0; q < 2; ++q) {
            float bv = b2[j0 + q];
            F2s[(j0 + q) * PAD + p0]     = fmaxf(acc0[q] + bv, 0.f);
            F2s[(j0 + q) * PAD + p0 + 1] = fmaxf(acc1[q] + bv, 0.f);
        }
    }
    __syncthreads();

    // ---- layer 3 (no relu): pq[g][j] = sum_c F2[g][c]*w3[c][j] ----
    {
        const int j = tid & 31;
        const int g = tid >> 5;       // 0..7
        float acc = 0.f;
        #pragma unroll 8
        for (int c = 0; c < 128; ++c)
            acc = fmaf(F2s[c * PAD + g], w3[c * 32 + j], acc);
        int point = base + g;
        float val = (point < NPTS) ? acc : (b3[j] - acc);
        pq[(size_t)point * 32 + j] = val;   // coalesced
    }
}

// ---------------------------------------------------------------------------
// Kernel 2: out[m][n] = b4 + sum_k w4[k] * relu(p1[m][k] + q2[n][k])
// Grid: (4 n-tiles, 128 m-tiles) = 512 blocks, 256 threads (one n, 8 m's).
// ---------------------------------------------------------------------------
__global__ __launch_bounds__(256) void pair_kernel(
    const float* __restrict__ pq,
    const float* __restrict__ w4,
    const float* __restrict__ b4,
    float* __restrict__ out)
{
    __shared__ float P1s[8 * 32];
    __shared__ float w4s[32];

    const int tid = threadIdx.x;
    const int n = blockIdx.x * 256 + tid;
    const int m0 = blockIdx.y * 8;

    float q[32];
    const float* q2 = pq + (size_t)(NPTS + n) * 32;
    #pragma unroll
    for (int k = 0; k < 32; ++k) q[k] = q2[k];

    if (tid < 8 * 32) P1s[tid] = pq[(size_t)m0 * 32 + tid];
    if (tid < 32) w4s[tid] = w4[tid];
    __syncthreads();

    const float b4v = b4[0];
    #pragma unroll
    for (int mm = 0; mm < 8; ++mm) {
        float acc = b4v;
        #pragma unroll
        for (int k = 0; k < 32; ++k) {
            float t = P1s[mm * 32 + k] + q[k];
            acc = fmaf(w4s[k], fmaxf(t, 0.f), acc);
        }
        out[(size_t)(m0 + mm) * 1024 + n] = acc;     // coalesced over n
    }
}

extern "C" void kernel_launch(void* const* d_in, const int* in_sizes, int n_in,
                              void* d_out, int out_size, void* d_ws, size_t ws_size,
                              hipStream_t stream) {
    const float* feature = (const float*)d_in[0];
    const int*   idx1    = (const int*)d_in[1];
    const int*   idx2    = (const int*)d_in[2];
    const float* w1      = (const float*)d_in[3];
    const float* b1      = (const float*)d_in[4];
    const float* w2      = (const float*)d_in[5];
    const float* b2      = (const float*)d_in[6];
    const float* w3      = (const float*)d_in[7];
    const float* b3      = (const float*)d_in[8];
    const float* w4      = (const float*)d_in[9];
    const float* b4      = (const float*)d_in[10];
    float* out = (float*)d_out;

    float* X  = (float*)d_ws;                       // 2048*256*4 = 2 MB
    float* pq = (float*)d_ws + 2048 * 256;          // 2048*32*4 = 256 KB

    gather_kernel<<<2048, 256, 0, stream>>>(feature, idx1, idx2, X);

    mlp_kernel<<<2048 / PPB, 256, 0, stream>>>(
        X, w1, b1, w2, b2, w3, b3, pq);

    pair_kernel<<<dim3(4, 128), 256, 0, stream>>>(pq, w4, b4, out);
}

// Round 4
// 376.645 us; speedup vs baseline: 1.0681x; 1.0093x over previous
//
#include <hip/hip_runtime.h>

#define NPTS 1024
#define NC 256
#define NH 360
#define NW 360
#define NHW (NH * NW)
#define NCHW (NC * NHW)
#define PPB 8       // points per MLP block
#define PAD 12      // LDS row stride for [c][p] activation tiles

// ---------------------------------------------------------------------------
// Kernel 1: fused gather + register-tiled 3-layer MLP.
// 8 points/block, 512 threads (8 waves/CU), 256 blocks.
// Gather goes straight into the transposed LDS tile (no X round-trip).
// Writes pq[2048][32]: rows 0..1023 = f1 @ w3, rows 1024..2047 = b3 - f2 @ w3.
// ---------------------------------------------------------------------------
__global__ __launch_bounds__(512) void mlp_kernel(
    const float* __restrict__ feature,
    const int* __restrict__ idx1,
    const int* __restrict__ idx2,
    const float* __restrict__ w1, const float* __restrict__ b1,
    const float* __restrict__ w2, const float* __restrict__ b2,
    const float* __restrict__ w3, const float* __restrict__ b3,
    float* __restrict__ pq)
{
    __shared__ float Xs[256 * PAD];   // [c][p], 12 KB
    __shared__ float H1s[256 * PAD];  // [j][p], 12 KB
    __shared__ float F2s[128 * PAD];  // [j][p], 6 KB

    const int tid = threadIdx.x;      // 0..511
    const int base = blockIdx.x * PPB;

    // ---- fused gather: Xs[c][p] = feature[b_p, c, h_p, w_p] ----
    // 512 threads x 4 points each; all 4 loads issued independently.
    {
        const int c = tid & 255;
        const int pg = (tid >> 8) * 4;            // 0 or 4
        float v[4];
        #pragma unroll
        for (int i = 0; i < 4; ++i) {
            int point = base + pg + i;
            int col = point & (NPTS - 1);
            const int* idx = (point < NPTS) ? idx1 : idx2;
            int bb = idx[col];                     // uniform per (block,i): scalar loads
            int hh = idx[NPTS + col];
            int ww = idx[2 * NPTS + col];
            v[i] = feature[(size_t)bb * NCHW + (size_t)c * NHW + hh * NW + ww];
        }
        #pragma unroll
        for (int i = 0; i < 4; ++i)
            Xs[c * PAD + pg + i] = v[i];
    }
    __syncthreads();

    const int jt = tid & 63;          // weight-vector lane
    const int pt = tid >> 6;          // 0..7 -> point

    // ---- layer 1: 256 -> 256, each thread: 1 point x 4 outputs ----
    {
        const float4* w1v = (const float4*)w1;    // w1v[c*64 + jt]
        float acc[4] = {0.f, 0.f, 0.f, 0.f};
        #pragma unroll 8
        for (int c = 0; c < 256; ++c) {
            float4 wv = w1v[c * 64 + jt];
            float a = Xs[c * PAD + pt];
            acc[0] = fmaf(a, wv.x, acc[0]);
            acc[1] = fmaf(a, wv.y, acc[1]);
            acc[2] = fmaf(a, wv.z, acc[2]);
            acc[3] = fmaf(a, wv.w, acc[3]);
        }
        const int j0 = jt * 4;
        #pragma unroll
        for (int q = 0; q < 4; ++q)
            H1s[(j0 + q) * PAD + pt] = fmaxf(acc[q] + b1[j0 + q], 0.f);
    }
    __syncthreads();

    // ---- layer 2: 256 -> 128, each thread: 1 point x 2 outputs ----
    {
        const float2* w2v = (const float2*)w2;    // w2v[c*64 + jt]
        float acc[2] = {0.f, 0.f};
        #pragma unroll 8
        for (int c = 0; c < 256; ++c) {
            float2 wv = w2v[c * 64 + jt];
            float a = H1s[c * PAD + pt];
            acc[0] = fmaf(a, wv.x, acc[0]);
            acc[1] = fmaf(a, wv.y, acc[1]);
        }
        const int j0 = jt * 2;
        #pragma unroll
        for (int q = 0; q < 2; ++q)
            F2s[(j0 + q) * PAD + pt] = fmaxf(acc[q] + b2[j0 + q], 0.f);
    }
    __syncthreads();

    // ---- layer 3 (no relu): pq[g][j] = sum_c F2[g][c]*w3[c][j] ----
    if (tid < 256) {
        const int j = tid & 31;
        const int g = tid >> 5;       // 0..7
        float acc = 0.f;
        #pragma unroll 8
        for (int c = 0; c < 128; ++c)
            acc = fmaf(F2s[c * PAD + g], w3[c * 32 + j], acc);
        int point = base + g;
        float val = (point < NPTS) ? acc : (b3[j] - acc);
        pq[(size_t)point * 32 + j] = val;   // coalesced
    }
}

// ---------------------------------------------------------------------------
// Kernel 2: out[m][n] = b4 + sum_k w4[k] * relu(p1[m][k] + q2[n][k])
// Grid: (4 n-tiles, 128 m-tiles) = 512 blocks, 256 threads (one n, 8 m's).
// ---------------------------------------------------------------------------
__global__ __launch_bounds__(256) void pair_kernel(
    const float* __restrict__ pq,
    const float* __restrict__ w4,
    const float* __restrict__ b4,
    float* __restrict__ out)
{
    __shared__ float P1s[8 * 32];
    __shared__ float w4s[32];

    const int tid = threadIdx.x;
    const int n = blockIdx.x * 256 + tid;
    const int m0 = blockIdx.y * 8;

    float q[32];
    const float* q2 = pq + (size_t)(NPTS + n) * 32;
    #pragma unroll
    for (int k = 0; k < 32; ++k) q[k] = q2[k];

    if (tid < 8 * 32) P1s[tid] = pq[(size_t)m0 * 32 + tid];
    if (tid < 32) w4s[tid] = w4[tid];
    __syncthreads();

    const float b4v = b4[0];
    #pragma unroll
    for (int mm = 0; mm < 8; ++mm) {
        float acc = b4v;
        #pragma unroll
        for (int k = 0; k < 32; ++k) {
            float t = P1s[mm * 32 + k] + q[k];
            acc = fmaf(w4s[k], fmaxf(t, 0.f), acc);
        }
        out[(size_t)(m0 + mm) * 1024 + n] = acc;     // coalesced over n
    }
}

extern "C" void kernel_launch(void* const* d_in, const int* in_sizes, int n_in,
                              void* d_out, int out_size, void* d_ws, size_t ws_size,
                              hipStream_t stream) {
    const float* feature = (const float*)d_in[0];
    const int*   idx1    = (const int*)d_in[1];
    const int*   idx2    = (const int*)d_in[2];
    const float* w1      = (const float*)d_in[3];
    const float* b1      = (const float*)d_in[4];
    const float* w2      = (const float*)d_in[5];
    const float* b2      = (const float*)d_in[6];
    const float* w3      = (const float*)d_in[7];
    const float* b3      = (const float*)d_in[8];
    const float* w4      = (const float*)d_in[9];
    const float* b4      = (const float*)d_in[10];
    float* out = (float*)d_out;

    float* pq = (float*)d_ws;                       // 2048*32*4 = 256 KB

    mlp_kernel<<<2048 / PPB, 512, 0, stream>>>(
        feature, idx1, idx2, w1, b1, w2, b2, w3, b3, pq);

    pair_kernel<<<dim3(4, 128), 256, 0, stream>>>(pq, w4, b4, out);
}